// Round 20
// baseline (392.475 us; speedup 1.0000x reference)
//
#include <hip/hip_runtime.h>

#define N_NODES 200000
#define N_EDGES 800000
#define IN_DIM 768
#define HID 128
#define NG 1024
#define CAP 32   // per-node edge bucket capacity; deg ~ Poisson(4), P(overflow) ~ 3e-13

// MFMA GEMM tile: BM=128, BKT=64 (256B per row-visit -> better DRAM page efficiency)
#define BM 128
#define BKT 64
#define NT (IN_DIM / BKT)     // 12
#define GEMM_TILES ((N_NODES + BM - 1) / BM)    // 1563

// bin tail blocks (appended after gemm blocks in the same dispatch)
#define BIN_BLKS 256
#define BIN_STRIDE (BIN_BLKS * 256)

typedef _Float16 f16x8 __attribute__((ext_vector_type(8)));
typedef float f32x4 __attribute__((ext_vector_type(4)));

__device__ __forceinline__ void gload_lds16(const void* g, void* l) {
  __builtin_amdgcn_global_load_lds((const __attribute__((address_space(1))) void*)g,
                                   (__attribute__((address_space(3))) void*)l, 16, 0, 0);
}

__device__ inline void unpack16(unsigned u, float& a, float& b) {
  union { unsigned v; _Float16 f[2]; } c; c.v = u;
  a = (float)c.f[0]; b = (float)c.f[1];
}
__device__ inline unsigned pack16(float a, float b) {
  union { unsigned v; _Float16 f[2]; } c;
  c.f[0] = (_Float16)a; c.f[1] = (_Float16)b;
  return c.v;
}

// ---------------- prep0: zero cursor + W-transpose (one dispatch) ----------------
__global__ __launch_bounds__(256) void k_prep0(int* __restrict__ cursor,
                                               const float* __restrict__ W, _Float16* __restrict__ WT) {
  int gid = blockIdx.x * 256 + threadIdx.x;
  if (gid < N_NODES) cursor[gid] = 0;
  if (gid < IN_DIM * HID) {
    int k = gid / HID, n = gid % HID;
    WT[(size_t)n * IN_DIM + k] = (_Float16)W[gid];
  }
}

// ---------------- fused: gemm (A-only LDS, B register-prefetched) + bin (tail) ----------------
__global__ __launch_bounds__(256, 2) void k_fused(const float* __restrict__ x,
                                                  const _Float16* __restrict__ WT,
                                                  _Float16* __restrict__ h16,
                                                  const int* __restrict__ row, const int* __restrict__ col,
                                                  int* __restrict__ cursor, int* __restrict__ ew) {
  __shared__ __align__(16) char arena[65536];   // A dbuf: 2 x 128 rows x 256 B

  if (blockIdx.x >= GEMM_TILES) {
    // ---- bin branch (hidden in gemm occupancy tail) ----
    int gid = ((int)blockIdx.x - GEMM_TILES) * 256 + threadIdx.x;
    for (int e = gid; e < N_EDGES; e += BIN_STRIDE) {
      int c = col[e];
      int slot = atomicAdd(&cursor[c], 1);
      if (slot < CAP) ew[(size_t)c * CAP + slot] = row[e];
    }
    return;
  }

  // ---- gemm branch ----
  const int t = threadIdx.x;
  const int lane = t & 63;
  const int wid = t >> 6;
  const int bm = blockIdx.x * BM;

  f32x4 acc[2][8];
#pragma unroll
  for (int i = 0; i < 2; ++i)
#pragma unroll
    for (int j = 0; j < 8; ++j) acc[i][j] = (f32x4){0.f, 0.f, 0.f, 0.f};

  const int lr = lane & 15;               // A row / B col within 16-tile
  const int lk = (lane >> 4) * 8;         // K offset (elements) within 32-slice

  // A staging: wave wid stages rows wid*32..+31 in 8 passes of 4 rows (1 KB each).
  // slot swizzle: phys slot s holds logical slot s ^ (row & 15)  (16B slots, 16/row)
  auto stage = [&](int k0, int dbuf) {    // 8 gload_lds per thread, A only
    char* bA = arena + dbuf * 32768;
#pragma unroll
    for (int p = 0; p < 8; ++p) {
      int rbase = wid * 32 + p * 4;
      int r = rbase + (lane >> 4);
      int grow = bm + r; if (grow >= N_NODES) grow = N_NODES - 1;
      int lslot = (lane & 15) ^ (r & 15);       // pre-swizzled global source
      gload_lds16(x + (size_t)grow * IN_DIM + k0 + lslot * 4,
                  bA + rbase * 256);            // wave-uniform dest; HW adds lane*16
    }
  };

  f16x8 breg[2][2][8];   // [buf][ks][ct] B fragments, register-resident (L2-sourced)

  stage(0, 0);
#pragma unroll
  for (int ks = 0; ks < 2; ++ks)
#pragma unroll
    for (int ct = 0; ct < 8; ++ct)
      breg[0][ks][ct] = *(const f16x8*)(WT + (size_t)(ct * 16 + lr) * IN_DIM + ks * 32 + lk);
  __syncthreads();

#pragma unroll
  for (int tt = 0; tt < NT; ++tt) {       // fully unrolled -> all breg indices static
    const int cur = tt & 1;
    if (tt + 1 < NT) {
      stage((tt + 1) * BKT, cur ^ 1);
#pragma unroll
      for (int ks = 0; ks < 2; ++ks)
#pragma unroll
        for (int ct = 0; ct < 8; ++ct)
          breg[cur ^ 1][ks][ct] = *(const f16x8*)(WT + (size_t)(ct * 16 + lr) * IN_DIM
                                                  + (tt + 1) * BKT + ks * 32 + lk);
    }
    const char* bA = arena + cur * 32768;
#pragma unroll
    for (int ks = 0; ks < 2; ++ks) {
      f16x8 af[2];
#pragma unroll
      for (int rt = 0; rt < 2; ++rt) {
        int r = wid * 32 + rt * 16 + lr;
        const char* rb = bA + r * 256;
        int s0 = ks * 8 + ((lane >> 4) << 1);   // logical 16B slot
        float4 lo = *(const float4*)(rb + ((s0 ^ lr) << 4));
        float4 hi = *(const float4*)(rb + (((s0 + 1) ^ lr) << 4));
        af[rt][0] = (_Float16)lo.x; af[rt][1] = (_Float16)lo.y;
        af[rt][2] = (_Float16)lo.z; af[rt][3] = (_Float16)lo.w;
        af[rt][4] = (_Float16)hi.x; af[rt][5] = (_Float16)hi.y;
        af[rt][6] = (_Float16)hi.z; af[rt][7] = (_Float16)hi.w;
      }
#pragma unroll
      for (int ct = 0; ct < 8; ++ct) {
        acc[0][ct] = __builtin_amdgcn_mfma_f32_16x16x32_f16(af[0], breg[cur][ks][ct], acc[0][ct], 0, 0, 0);
        acc[1][ct] = __builtin_amdgcn_mfma_f32_16x16x32_f16(af[1], breg[cur][ks][ct], acc[1][ct], 0, 0, 0);
      }
    }
    __syncthreads();
  }

  // ---- epilogue: repack through LDS (32 KB of arena), coalesced fp16 stores ----
  _Float16* hb = (_Float16*)arena;
  const int dcol = lane & 15;
  const int drow = (lane >> 4) * 4;
#pragma unroll
  for (int rt = 0; rt < 2; ++rt)
#pragma unroll
    for (int j = 0; j < 4; ++j) {
      int rl = wid * 32 + rt * 16 + drow + j;
#pragma unroll
      for (int ct = 0; ct < 8; ++ct)
        hb[rl * HID + ct * 16 + dcol] = (_Float16)acc[rt][ct][j];
    }
  __syncthreads();
#pragma unroll
  for (int q = 0; q < 8; ++q) {
    int f = t + 256 * q;
    int rowl = f >> 4, seg = f & 15;
    int grow = bm + rowl;
    if (grow < N_NODES)
      ((uint4*)(h16 + (size_t)grow * HID))[seg] = ((const uint4*)hb)[f];
  }
}

// ---------------- gather: depth-2 pipelined node pairs (R18 form) ----------------
__global__ __launch_bounds__(256) void k_gather(const _Float16* __restrict__ h16,
                                                const int* __restrict__ cursor,
                                                const int* __restrict__ ew,
                                                const float* __restrict__ b_conv,
                                                _Float16* __restrict__ hout16) {
  int gid = blockIdx.x * 256 + threadIdx.x;
  int wv = gid >> 6, lane = gid & 63;
  int n0 = wv * 4;
  if (n0 >= N_NODES) return;
  const int grp = lane >> 4;
  const int fl = lane & 15;
  const int j32 = fl + 16 * grp;
  const unsigned* h32 = (const unsigned*)h16;
  unsigned* ho32 = (unsigned*)hout16;
  const float bc0 = b_conv[2 * j32], bc1 = b_conv[2 * j32 + 1];

#pragma unroll
  for (int p = 0; p < 2; ++p) {
    const int iA = n0 + 2 * p;
    const int iB = iA + 1;
    const bool vA = iA < N_NODES, vB = iB < N_NODES;
    const int cA_idx = vA ? iA : N_NODES - 1;
    const int cB_idx = vB ? iB : N_NODES - 1;

    int cntA = cursor[cA_idx];
    int cntB = cursor[cB_idx];
    unsigned selfA = h32[(size_t)cA_idx * 64 + j32];
    unsigned selfB = h32[(size_t)cB_idx * 64 + j32];
    int bkA = (grp < cntA) ? ew[(size_t)cA_idx * CAP + grp] : 0;
    int bkB = (grp < cntB) ? ew[(size_t)cB_idx * CAP + grp] : 0;

    float diA = rsqrtf((float)(cntA + 1));
    float diB = rsqrtf((float)(cntB + 1));
    int mA = cntA > CAP ? CAP : cntA;
    int mB = cntB > CAP ? CAP : cntB;

    float aA[8], aB[8];
#pragma unroll
    for (int q = 0; q < 8; ++q) { aA[q] = 0.f; aB[q] = 0.f; }

    {
      bool eA = grp < (mA < 4 ? mA : 4);
      bool eB = grp < (mB < 4 ? mB : 4);
      float wA = 0.f, wB = 0.f;
      unsigned uA0 = 0, uA1 = 0, uA2 = 0, uA3 = 0;
      unsigned uB0 = 0, uB1 = 0, uB2 = 0, uB3 = 0;
      if (eA) {
        wA = rsqrtf((float)(cursor[bkA] + 1)) * diA;
        const unsigned* hr = h32 + (size_t)bkA * 64;
        uA0 = hr[fl]; uA1 = hr[fl + 16]; uA2 = hr[fl + 32]; uA3 = hr[fl + 48];
      }
      if (eB) {
        wB = rsqrtf((float)(cursor[bkB] + 1)) * diB;
        const unsigned* hr = h32 + (size_t)bkB * 64;
        uB0 = hr[fl]; uB1 = hr[fl + 16]; uB2 = hr[fl + 32]; uB3 = hr[fl + 48];
      }
      float f0, f1;
      unpack16(uA0, f0, f1); aA[0] = fmaf(f0, wA, aA[0]); aA[1] = fmaf(f1, wA, aA[1]);
      unpack16(uA1, f0, f1); aA[2] = fmaf(f0, wA, aA[2]); aA[3] = fmaf(f1, wA, aA[3]);
      unpack16(uA2, f0, f1); aA[4] = fmaf(f0, wA, aA[4]); aA[5] = fmaf(f1, wA, aA[5]);
      unpack16(uA3, f0, f1); aA[6] = fmaf(f0, wA, aA[6]); aA[7] = fmaf(f1, wA, aA[7]);
      unpack16(uB0, f0, f1); aB[0] = fmaf(f0, wB, aB[0]); aB[1] = fmaf(f1, wB, aB[1]);
      unpack16(uB1, f0, f1); aB[2] = fmaf(f0, wB, aB[2]); aB[3] = fmaf(f1, wB, aB[3]);
      unpack16(uB2, f0, f1); aB[4] = fmaf(f0, wB, aB[4]); aB[5] = fmaf(f1, wB, aB[5]);
      unpack16(uB3, f0, f1); aB[6] = fmaf(f0, wB, aB[6]); aB[7] = fmaf(f1, wB, aB[7]);
    }

    int mMax = mA > mB ? mA : mB;
    for (int c = 4; c < mMax; c += 4) {
      bool eA = c + grp < mA;
      bool eB = c + grp < mB;
      int rA = eA ? ew[(size_t)iA * CAP + c + grp] : 0;
      int rB = eB ? ew[(size_t)iB * CAP + c + grp] : 0;
      float wA = 0.f, wB = 0.f;
      unsigned uA0 = 0, uA1 = 0, uA2 = 0, uA3 = 0;
      unsigned uB0 = 0, uB1 = 0, uB2 = 0, uB3 = 0;
      if (eA) {
        wA = rsqrtf((float)(cursor[rA] + 1)) * diA;
        const unsigned* hr = h32 + (size_t)rA * 64;
        uA0 = hr[fl]; uA1 = hr[fl + 16]; uA2 = hr[fl + 32]; uA3 = hr[fl + 48];
      }
      if (eB) {
        wB = rsqrtf((float)(cursor[rB] + 1)) * diB;
        const unsigned* hr = h32 + (size_t)rB * 64;
        uB0 = hr[fl]; uB1 = hr[fl + 16]; uB2 = hr[fl + 32]; uB3 = hr[fl + 48];
      }
      float f0, f1;
      unpack16(uA0, f0, f1); aA[0] = fmaf(f0, wA, aA[0]); aA[1] = fmaf(f1, wA, aA[1]);
      unpack16(uA1, f0, f1); aA[2] = fmaf(f0, wA, aA[2]); aA[3] = fmaf(f1, wA, aA[3]);
      unpack16(uA2, f0, f1); aA[4] = fmaf(f0, wA, aA[4]); aA[5] = fmaf(f1, wA, aA[5]);
      unpack16(uA3, f0, f1); aA[6] = fmaf(f0, wA, aA[6]); aA[7] = fmaf(f1, wA, aA[7]);
      unpack16(uB0, f0, f1); aB[0] = fmaf(f0, wB, aB[0]); aB[1] = fmaf(f1, wB, aB[1]);
      unpack16(uB1, f0, f1); aB[2] = fmaf(f0, wB, aB[2]); aB[3] = fmaf(f1, wB, aB[3]);
      unpack16(uB2, f0, f1); aB[4] = fmaf(f0, wB, aB[4]); aB[5] = fmaf(f1, wB, aB[5]);
      unpack16(uB3, f0, f1); aB[6] = fmaf(f0, wB, aB[6]); aB[7] = fmaf(f1, wB, aB[7]);
    }

#pragma unroll
    for (int q = 0; q < 8; ++q) {
      aA[q] += __shfl_xor(aA[q], 16);
      aA[q] += __shfl_xor(aA[q], 32);
      aB[q] += __shfl_xor(aB[q], 16);
      aB[q] += __shfl_xor(aB[q], 32);
    }
    float rA0 = aA[0], rA1 = aA[1], rB0 = aB[0], rB1 = aB[1];
    if (grp == 1) { rA0 = aA[2]; rA1 = aA[3]; rB0 = aB[2]; rB1 = aB[3]; }
    else if (grp == 2) { rA0 = aA[4]; rA1 = aA[5]; rB0 = aB[4]; rB1 = aB[5]; }
    else if (grp == 3) { rA0 = aA[6]; rA1 = aA[7]; rB0 = aB[6]; rB1 = aB[7]; }

    if (vA) {
      float swA = diA * diA, s0, s1;
      unpack16(selfA, s0, s1);
      float v0 = fmaxf(fmaf(s0, swA, rA0) + bc0, 0.f);
      float v1 = fmaxf(fmaf(s1, swA, rA1) + bc1, 0.f);
      ho32[(size_t)iA * 64 + j32] = pack16(v0, v1);
    }
    if (vB) {
      float swB = diB * diB, s0, s1;
      unpack16(selfB, s0, s1);
      float v0 = fmaxf(fmaf(s0, swB, rB0) + bc0, 0.f);
      float v1 = fmaxf(fmaf(s1, swB, rB1) + bc1, 0.f);
      ho32[(size_t)iB * 64 + j32] = pack16(v0, v1);
    }
  }
}

// ---------------- fused head: pool(scan rows, 4x unrolled) + idx0 + news + hidden + out ----------------
__global__ __launch_bounds__(128) void k_head(const float* __restrict__ x,
                                              const int* __restrict__ batch,
                                              const _Float16* __restrict__ hout16,
                                              const float* __restrict__ W0, const float* __restrict__ b0,
                                              const float* __restrict__ W1, const float* __restrict__ b1,
                                              const float* __restrict__ W2, const float* __restrict__ b2,
                                              float* __restrict__ out) {
  __shared__ float xr[IN_DIM];
  __shared__ float pl[HID];
  __shared__ float nn[HID];
  __shared__ float red[4];
  int g = blockIdx.x, t = threadIdx.x;

  int lo = 0, hi = N_NODES;
  while (lo < hi) { int mid = (lo + hi) >> 1; if (batch[mid] < g) lo = mid + 1; else hi = mid; }
  int lo2 = 0, hi2 = N_NODES;
  int tgt = g + 1;
  while (lo2 < hi2) { int mid = (lo2 + hi2) >> 1; if (batch[mid] < tgt) lo2 = mid + 1; else hi2 = mid; }
  int i0 = lo < N_NODES ? lo : N_NODES - 1;

  const unsigned* ho32 = (const unsigned*)hout16;
  const int u = t >> 1, half = t & 1;
  float m = 0.f;
  int r = lo;
  for (; r + 3 < lo2; r += 4) {
    unsigned a = ho32[(size_t)r * 64 + u];
    unsigned b = ho32[(size_t)(r + 1) * 64 + u];
    unsigned c = ho32[(size_t)(r + 2) * 64 + u];
    unsigned d = ho32[(size_t)(r + 3) * 64 + u];
    float a0, a1, b0v, b1v, c0, c1, d0, d1;
    unpack16(a, a0, a1); unpack16(b, b0v, b1v);
    unpack16(c, c0, c1); unpack16(d, d0, d1);
    m = fmaxf(m, half ? a1 : a0);
    m = fmaxf(m, half ? b1v : b0v);
    m = fmaxf(m, half ? c1 : c0);
    m = fmaxf(m, half ? d1 : d0);
  }
  for (; r < lo2; ++r) {
    unsigned a = ho32[(size_t)r * 64 + u];
    float a0, a1; unpack16(a, a0, a1);
    m = fmaxf(m, half ? a1 : a0);
  }
  pl[t] = m;

  const float* xp = x + (size_t)i0 * IN_DIM;
  for (int k = t; k < IN_DIM; k += 128) xr[k] = xp[k];
  __syncthreads();

  float a = b0[t];
#pragma unroll 8
  for (int k = 0; k < IN_DIM; ++k) a = fmaf(xr[k], W0[(size_t)k * HID + t], a);
  nn[t] = fmaxf(a, 0.f);
  __syncthreads();

  float z = b1[t];
#pragma unroll 8
  for (int k = 0; k < HID; ++k) z = fmaf(pl[k], W1[(size_t)k * HID + t], z);
#pragma unroll 8
  for (int k = 0; k < HID; ++k) z = fmaf(nn[k], W1[(size_t)(HID + k) * HID + t], z);
  z = fmaxf(z, 0.f);
  float p0 = z * W2[2 * t], p1 = z * W2[2 * t + 1];
#pragma unroll
  for (int o = 32; o > 0; o >>= 1) {
    p0 += __shfl_down(p0, o);
    p1 += __shfl_down(p1, o);
  }
  if ((t & 63) == 0) { red[(t >> 6) * 2] = p0; red[(t >> 6) * 2 + 1] = p1; }
  __syncthreads();
  if (t == 0) {
    float l0 = b2[0] + red[0] + red[2];
    float l1 = b2[1] + red[1] + red[3];
    float mm = fmaxf(l0, l1);
    float lse = mm + logf(expf(l0 - mm) + expf(l1 - mm));
    out[g * 2 + 0] = l0 - lse;
    out[g * 2 + 1] = l1 - lse;
  }
}

extern "C" void kernel_launch(void* const* d_in, const int* in_sizes, int n_in,
                              void* d_out, int out_size, void* d_ws, size_t ws_size,
                              hipStream_t stream) {
  const float* x      = (const float*)d_in[0];
  const int* edge     = (const int*)d_in[1];
  const int* batch    = (const int*)d_in[2];
  const float* W_conv = (const float*)d_in[4];
  const float* b_conv = (const float*)d_in[5];
  const float* W0     = (const float*)d_in[6];
  const float* b0     = (const float*)d_in[7];
  const float* W1     = (const float*)d_in[8];
  const float* b1     = (const float*)d_in[9];
  const float* W2     = (const float*)d_in[10];
  const float* b2     = (const float*)d_in[11];
  float* out = (float*)d_out;

  const int* row = edge;
  const int* col = edge + N_EDGES;

  // workspace layout (bytes), 256B-aligned
  char* ws = (char*)d_ws;
  _Float16*  h16    = (_Float16*)(ws);                   //  51,200,000
  _Float16*  hout16 = (_Float16*)(ws + 51200000);        //  51,200,000
  int*       cursor = (int*)  (ws + 102400000);          //     800,000 (ends as exact degree)
  int*       ew     = (int*)  (ws + 103200000);          //  25,600,000 (CAP=32 buckets)
  _Float16*  WT     = (_Float16*)(ws + 128800000);       //     196,608

  // 4 dispatches; bin hidden in the gemm's occupancy tail
  k_prep0<<<(N_NODES + 255) / 256, 256, 0, stream>>>(cursor, W_conv, WT);
  k_fused<<<GEMM_TILES + BIN_BLKS, 256, 0, stream>>>(x, WT, h16, row, col, cursor, ew);
  k_gather<<<(((N_NODES + 3) / 4) * 64 + 255) / 256, 256, 0, stream>>>(h16, cursor, ew, b_conv, hout16);
  k_head<<<NG, 128, 0, stream>>>(x, batch, hout16, W0, b0, W1, b1, W2, b2, out);
}

// Round 21
// 329.084 us; speedup vs baseline: 1.1926x; 1.1926x over previous
//
#include <hip/hip_runtime.h>

#define N_NODES 200000
#define N_EDGES 800000
#define IN_DIM 768
#define HID 128
#define NG 1024
#define CAP 32   // per-node edge bucket capacity; deg ~ Poisson(4), P(overflow) ~ 3e-13

// MFMA GEMM tile (R18 proven config)
#define BM 128
#define BKT 32
#define NT (IN_DIM / BKT)     // 24
#define GEMM_TILES ((N_NODES + BM - 1) / BM)    // 1563

// bin tail blocks (appended after gemm blocks in the same dispatch)
#define BIN_BLKS 256
#define BIN_STRIDE (BIN_BLKS * 256)

typedef _Float16 f16x8 __attribute__((ext_vector_type(8)));
typedef float f32x4 __attribute__((ext_vector_type(4)));

__device__ __forceinline__ void gload_lds16(const void* g, void* l) {
  __builtin_amdgcn_global_load_lds((const __attribute__((address_space(1))) void*)g,
                                   (__attribute__((address_space(3))) void*)l, 16, 0, 0);
}

__device__ inline void unpack16(unsigned u, float& a, float& b) {
  union { unsigned v; _Float16 f[2]; } c; c.v = u;
  a = (float)c.f[0]; b = (float)c.f[1];
}
__device__ inline unsigned pack16(float a, float b) {
  union { unsigned v; _Float16 f[2]; } c;
  c.f[0] = (_Float16)a; c.f[1] = (_Float16)b;
  return c.v;
}

// ---------------- prep0: zero cursor + W-transpose (one dispatch) ----------------
__global__ __launch_bounds__(256) void k_prep0(int* __restrict__ cursor,
                                               const float* __restrict__ W, _Float16* __restrict__ WT) {
  int gid = blockIdx.x * 256 + threadIdx.x;
  if (gid < N_NODES) cursor[gid] = 0;
  if (gid < IN_DIM * HID) {
    int k = gid / HID, n = gid % HID;
    WT[(size_t)n * IN_DIM + k] = (_Float16)W[gid];
  }
}

// ---------------- fused: gemm (blocks 0..GEMM_TILES) + bin (tail blocks)  [R18] ----------------
__global__ __launch_bounds__(256, 3) void k_fused(const float* __restrict__ x,
                                                  const _Float16* __restrict__ WT,
                                                  _Float16* __restrict__ h16,
                                                  const int* __restrict__ row, const int* __restrict__ col,
                                                  int* __restrict__ cursor, int* __restrict__ ew) {
  __shared__ __align__(16) char arena[49152];   // 48 KB

  if (blockIdx.x >= GEMM_TILES) {
    // ---- bin branch (hidden in gemm occupancy tail) ----
    int gid = ((int)blockIdx.x - GEMM_TILES) * 256 + threadIdx.x;
    for (int e = gid; e < N_EDGES; e += BIN_STRIDE) {
      int c = col[e];
      int slot = atomicAdd(&cursor[c], 1);
      if (slot < CAP) ew[(size_t)c * CAP + slot] = row[e];
    }
    return;
  }

  // ---- gemm branch ----
  const int t = threadIdx.x;
  const int lane = t & 63;
  const int wid = t >> 6;
  const int bm = blockIdx.x * BM;

  f32x4 acc[2][8];
#pragma unroll
  for (int i = 0; i < 2; ++i)
#pragma unroll
    for (int j = 0; j < 8; ++j) acc[i][j] = (f32x4){0.f, 0.f, 0.f, 0.f};

  const int lr = lane & 15;
  const int s0 = (lane >> 4) * 2;
  const int bslot_r = lane >> 4;

  const int a_srow = lane >> 3;
  const int a_scol = ((lane & 7) ^ (lane >> 3)) * 4;
  const int b_srow = lane >> 2;
  const int b_scol = (((lane & 3) ^ ((lane >> 3) & 3)) * 8);

  auto stage = [&](int k0, int dbuf) {
    char* bA = arena + dbuf * 16384;
    char* bB = arena + 32768 + dbuf * 8192;
#pragma unroll
    for (int p = 0; p < 4; ++p) {
      int r = p * 32 + wid * 8 + a_srow;
      int grow = bm + r; if (grow >= N_NODES) grow = N_NODES - 1;
      gload_lds16(x + (size_t)grow * IN_DIM + k0 + a_scol, bA + p * 4096 + wid * 1024);
    }
#pragma unroll
    for (int p = 0; p < 2; ++p) {
      int r = p * 64 + wid * 16 + b_srow;
      gload_lds16(WT + (size_t)r * IN_DIM + k0 + b_scol, bB + p * 4096 + wid * 1024);
    }
  };

  stage(0, 0);
  __syncthreads();

  for (int tt = 0; tt < NT; ++tt) {
    const int cur = tt & 1;
    if (tt + 1 < NT) stage((tt + 1) * BKT, cur ^ 1);

    const char* bA = arena + cur * 16384;
    const char* bB = arena + 32768 + cur * 8192;

    f16x8 af[2];
#pragma unroll
    for (int rt = 0; rt < 2; ++rt) {
      int r = wid * 32 + rt * 16 + lr;
      const char* rb = bA + r * 128;
      int f = r & 7;
      float4 lo = *(const float4*)(rb + ((s0 ^ f) << 4));
      float4 hi = *(const float4*)(rb + (((s0 + 1) ^ f) << 4));
      af[rt][0] = (_Float16)lo.x; af[rt][1] = (_Float16)lo.y;
      af[rt][2] = (_Float16)lo.z; af[rt][3] = (_Float16)lo.w;
      af[rt][4] = (_Float16)hi.x; af[rt][5] = (_Float16)hi.y;
      af[rt][6] = (_Float16)hi.z; af[rt][7] = (_Float16)hi.w;
    }
#pragma unroll
    for (int ct = 0; ct < 8; ++ct) {
      int cr = ct * 16 + lr;
      f16x8 bf = *(const f16x8*)(bB + cr * 64 + ((bslot_r ^ ((cr >> 1) & 3)) << 4));
      acc[0][ct] = __builtin_amdgcn_mfma_f32_16x16x32_f16(af[0], bf, acc[0][ct], 0, 0, 0);
      acc[1][ct] = __builtin_amdgcn_mfma_f32_16x16x32_f16(af[1], bf, acc[1][ct], 0, 0, 0);
    }
    __syncthreads();
  }

  _Float16* hb = (_Float16*)arena;
  const int dcol = lane & 15;
  const int drow = (lane >> 4) * 4;
#pragma unroll
  for (int rt = 0; rt < 2; ++rt)
#pragma unroll
    for (int j = 0; j < 4; ++j) {
      int rl = wid * 32 + rt * 16 + drow + j;
#pragma unroll
      for (int ct = 0; ct < 8; ++ct)
        hb[rl * HID + ct * 16 + dcol] = (_Float16)acc[rt][ct][j];
    }
  __syncthreads();
#pragma unroll
  for (int q = 0; q < 8; ++q) {
    int f = t + 256 * q;
    int rowl = f >> 4, seg = f & 15;
    int grow = bm + rowl;
    if (grow < N_NODES)
      ((uint4*)(h16 + (size_t)grow * HID))[seg] = ((const uint4*)hb)[f];
  }
}

// ---------------- gather: depth-2 pipelined node pairs (R18) ----------------
__global__ __launch_bounds__(256) void k_gather(const _Float16* __restrict__ h16,
                                                const int* __restrict__ cursor,
                                                const int* __restrict__ ew,
                                                const float* __restrict__ b_conv,
                                                _Float16* __restrict__ hout16) {
  int gid = blockIdx.x * 256 + threadIdx.x;
  int wv = gid >> 6, lane = gid & 63;
  int n0 = wv * 4;
  if (n0 >= N_NODES) return;
  const int grp = lane >> 4;
  const int fl = lane & 15;
  const int j32 = fl + 16 * grp;
  const unsigned* h32 = (const unsigned*)h16;
  unsigned* ho32 = (unsigned*)hout16;
  const float bc0 = b_conv[2 * j32], bc1 = b_conv[2 * j32 + 1];

#pragma unroll
  for (int p = 0; p < 2; ++p) {
    const int iA = n0 + 2 * p;
    const int iB = iA + 1;
    const bool vA = iA < N_NODES, vB = iB < N_NODES;
    const int cA_idx = vA ? iA : N_NODES - 1;
    const int cB_idx = vB ? iB : N_NODES - 1;

    int cntA = cursor[cA_idx];
    int cntB = cursor[cB_idx];
    unsigned selfA = h32[(size_t)cA_idx * 64 + j32];
    unsigned selfB = h32[(size_t)cB_idx * 64 + j32];
    int bkA = (grp < cntA) ? ew[(size_t)cA_idx * CAP + grp] : 0;
    int bkB = (grp < cntB) ? ew[(size_t)cB_idx * CAP + grp] : 0;

    float diA = rsqrtf((float)(cntA + 1));
    float diB = rsqrtf((float)(cntB + 1));
    int mA = cntA > CAP ? CAP : cntA;
    int mB = cntB > CAP ? CAP : cntB;

    float aA[8], aB[8];
#pragma unroll
    for (int q = 0; q < 8; ++q) { aA[q] = 0.f; aB[q] = 0.f; }

    {
      bool eA = grp < (mA < 4 ? mA : 4);
      bool eB = grp < (mB < 4 ? mB : 4);
      float wA = 0.f, wB = 0.f;
      unsigned uA0 = 0, uA1 = 0, uA2 = 0, uA3 = 0;
      unsigned uB0 = 0, uB1 = 0, uB2 = 0, uB3 = 0;
      if (eA) {
        wA = rsqrtf((float)(cursor[bkA] + 1)) * diA;
        const unsigned* hr = h32 + (size_t)bkA * 64;
        uA0 = hr[fl]; uA1 = hr[fl + 16]; uA2 = hr[fl + 32]; uA3 = hr[fl + 48];
      }
      if (eB) {
        wB = rsqrtf((float)(cursor[bkB] + 1)) * diB;
        const unsigned* hr = h32 + (size_t)bkB * 64;
        uB0 = hr[fl]; uB1 = hr[fl + 16]; uB2 = hr[fl + 32]; uB3 = hr[fl + 48];
      }
      float f0, f1;
      unpack16(uA0, f0, f1); aA[0] = fmaf(f0, wA, aA[0]); aA[1] = fmaf(f1, wA, aA[1]);
      unpack16(uA1, f0, f1); aA[2] = fmaf(f0, wA, aA[2]); aA[3] = fmaf(f1, wA, aA[3]);
      unpack16(uA2, f0, f1); aA[4] = fmaf(f0, wA, aA[4]); aA[5] = fmaf(f1, wA, aA[5]);
      unpack16(uA3, f0, f1); aA[6] = fmaf(f0, wA, aA[6]); aA[7] = fmaf(f1, wA, aA[7]);
      unpack16(uB0, f0, f1); aB[0] = fmaf(f0, wB, aB[0]); aB[1] = fmaf(f1, wB, aB[1]);
      unpack16(uB1, f0, f1); aB[2] = fmaf(f0, wB, aB[2]); aB[3] = fmaf(f1, wB, aB[3]);
      unpack16(uB2, f0, f1); aB[4] = fmaf(f0, wB, aB[4]); aB[5] = fmaf(f1, wB, aB[5]);
      unpack16(uB3, f0, f1); aB[6] = fmaf(f0, wB, aB[6]); aB[7] = fmaf(f1, wB, aB[7]);
    }

    int mMax = mA > mB ? mA : mB;
    for (int c = 4; c < mMax; c += 4) {
      bool eA = c + grp < mA;
      bool eB = c + grp < mB;
      int rA = eA ? ew[(size_t)iA * CAP + c + grp] : 0;
      int rB = eB ? ew[(size_t)iB * CAP + c + grp] : 0;
      float wA = 0.f, wB = 0.f;
      unsigned uA0 = 0, uA1 = 0, uA2 = 0, uA3 = 0;
      unsigned uB0 = 0, uB1 = 0, uB2 = 0, uB3 = 0;
      if (eA) {
        wA = rsqrtf((float)(cursor[rA] + 1)) * diA;
        const unsigned* hr = h32 + (size_t)rA * 64;
        uA0 = hr[fl]; uA1 = hr[fl + 16]; uA2 = hr[fl + 32]; uA3 = hr[fl + 48];
      }
      if (eB) {
        wB = rsqrtf((float)(cursor[rB] + 1)) * diB;
        const unsigned* hr = h32 + (size_t)rB * 64;
        uB0 = hr[fl]; uB1 = hr[fl + 16]; uB2 = hr[fl + 32]; uB3 = hr[fl + 48];
      }
      float f0, f1;
      unpack16(uA0, f0, f1); aA[0] = fmaf(f0, wA, aA[0]); aA[1] = fmaf(f1, wA, aA[1]);
      unpack16(uA1, f0, f1); aA[2] = fmaf(f0, wA, aA[2]); aA[3] = fmaf(f1, wA, aA[3]);
      unpack16(uA2, f0, f1); aA[4] = fmaf(f0, wA, aA[4]); aA[5] = fmaf(f1, wA, aA[5]);
      unpack16(uA3, f0, f1); aA[6] = fmaf(f0, wA, aA[6]); aA[7] = fmaf(f1, wA, aA[7]);
      unpack16(uB0, f0, f1); aB[0] = fmaf(f0, wB, aB[0]); aB[1] = fmaf(f1, wB, aB[1]);
      unpack16(uB1, f0, f1); aB[2] = fmaf(f0, wB, aB[2]); aB[3] = fmaf(f1, wB, aB[3]);
      unpack16(uB2, f0, f1); aB[4] = fmaf(f0, wB, aB[4]); aB[5] = fmaf(f1, wB, aB[5]);
      unpack16(uB3, f0, f1); aB[6] = fmaf(f0, wB, aB[6]); aB[7] = fmaf(f1, wB, aB[7]);
    }

#pragma unroll
    for (int q = 0; q < 8; ++q) {
      aA[q] += __shfl_xor(aA[q], 16);
      aA[q] += __shfl_xor(aA[q], 32);
      aB[q] += __shfl_xor(aB[q], 16);
      aB[q] += __shfl_xor(aB[q], 32);
    }
    float rA0 = aA[0], rA1 = aA[1], rB0 = aB[0], rB1 = aB[1];
    if (grp == 1) { rA0 = aA[2]; rA1 = aA[3]; rB0 = aB[2]; rB1 = aB[3]; }
    else if (grp == 2) { rA0 = aA[4]; rA1 = aA[5]; rB0 = aB[4]; rB1 = aB[5]; }
    else if (grp == 3) { rA0 = aA[6]; rA1 = aA[7]; rB0 = aB[6]; rB1 = aB[7]; }

    if (vA) {
      float swA = diA * diA, s0, s1;
      unpack16(selfA, s0, s1);
      float v0 = fmaxf(fmaf(s0, swA, rA0) + bc0, 0.f);
      float v1 = fmaxf(fmaf(s1, swA, rA1) + bc1, 0.f);
      ho32[(size_t)iA * 64 + j32] = pack16(v0, v1);
    }
    if (vB) {
      float swB = diB * diB, s0, s1;
      unpack16(selfB, s0, s1);
      float v0 = fmaxf(fmaf(s0, swB, rB0) + bc0, 0.f);
      float v1 = fmaxf(fmaf(s1, swB, rB1) + bc1, 0.f);
      ho32[(size_t)iB * 64 + j32] = pack16(v0, v1);
    }
  }
}

// ---------------- fused head (R18 + parallel binary searches) ----------------
__global__ __launch_bounds__(128) void k_head(const float* __restrict__ x,
                                              const int* __restrict__ batch,
                                              const _Float16* __restrict__ hout16,
                                              const float* __restrict__ W0, const float* __restrict__ b0,
                                              const float* __restrict__ W1, const float* __restrict__ b1,
                                              const float* __restrict__ W2, const float* __restrict__ b2,
                                              float* __restrict__ out) {
  __shared__ float xr[IN_DIM];
  __shared__ float pl[HID];
  __shared__ float nn[HID];
  __shared__ float red[4];
  __shared__ int bounds[2];
  int g = blockIdx.x, t = threadIdx.x;

  // two binary searches in parallel (warp 0 lane 0: lo; warp 1 lane 0: lo2)
  if (t == 0 || t == 64) {
    int tgt = g + (t >> 6);
    int lo = 0, hi = N_NODES;
    while (lo < hi) { int mid = (lo + hi) >> 1; if (batch[mid] < tgt) lo = mid + 1; else hi = mid; }
    bounds[t >> 6] = lo;
  }
  __syncthreads();
  int lo = bounds[0], lo2 = bounds[1];
  int i0 = lo < N_NODES ? lo : N_NODES - 1;

  const unsigned* ho32 = (const unsigned*)hout16;
  const int u = t >> 1, half = t & 1;
  float m = 0.f;
  int r = lo;
  for (; r + 3 < lo2; r += 4) {
    unsigned a = ho32[(size_t)r * 64 + u];
    unsigned b = ho32[(size_t)(r + 1) * 64 + u];
    unsigned c = ho32[(size_t)(r + 2) * 64 + u];
    unsigned d = ho32[(size_t)(r + 3) * 64 + u];
    float a0, a1, b0v, b1v, c0, c1, d0, d1;
    unpack16(a, a0, a1); unpack16(b, b0v, b1v);
    unpack16(c, c0, c1); unpack16(d, d0, d1);
    m = fmaxf(m, half ? a1 : a0);
    m = fmaxf(m, half ? b1v : b0v);
    m = fmaxf(m, half ? c1 : c0);
    m = fmaxf(m, half ? d1 : d0);
  }
  for (; r < lo2; ++r) {
    unsigned a = ho32[(size_t)r * 64 + u];
    float a0, a1; unpack16(a, a0, a1);
    m = fmaxf(m, half ? a1 : a0);
  }
  pl[t] = m;

  const float* xp = x + (size_t)i0 * IN_DIM;
  for (int k = t; k < IN_DIM; k += 128) xr[k] = xp[k];
  __syncthreads();

  float a = b0[t];
#pragma unroll 8
  for (int k = 0; k < IN_DIM; ++k) a = fmaf(xr[k], W0[(size_t)k * HID + t], a);
  nn[t] = fmaxf(a, 0.f);
  __syncthreads();

  float z = b1[t];
#pragma unroll 8
  for (int k = 0; k < HID; ++k) z = fmaf(pl[k], W1[(size_t)k * HID + t], z);
#pragma unroll 8
  for (int k = 0; k < HID; ++k) z = fmaf(nn[k], W1[(size_t)(HID + k) * HID + t], z);
  z = fmaxf(z, 0.f);
  float p0 = z * W2[2 * t], p1 = z * W2[2 * t + 1];
#pragma unroll
  for (int o = 32; o > 0; o >>= 1) {
    p0 += __shfl_down(p0, o);
    p1 += __shfl_down(p1, o);
  }
  if ((t & 63) == 0) { red[(t >> 6) * 2] = p0; red[(t >> 6) * 2 + 1] = p1; }
  __syncthreads();
  if (t == 0) {
    float l0 = b2[0] + red[0] + red[2];
    float l1 = b2[1] + red[1] + red[3];
    float mm = fmaxf(l0, l1);
    float lse = mm + logf(expf(l0 - mm) + expf(l1 - mm));
    out[g * 2 + 0] = l0 - lse;
    out[g * 2 + 1] = l1 - lse;
  }
}

extern "C" void kernel_launch(void* const* d_in, const int* in_sizes, int n_in,
                              void* d_out, int out_size, void* d_ws, size_t ws_size,
                              hipStream_t stream) {
  const float* x      = (const float*)d_in[0];
  const int* edge     = (const int*)d_in[1];
  const int* batch    = (const int*)d_in[2];
  const float* W_conv = (const float*)d_in[4];
  const float* b_conv = (const float*)d_in[5];
  const float* W0     = (const float*)d_in[6];
  const float* b0     = (const float*)d_in[7];
  const float* W1     = (const float*)d_in[8];
  const float* b1     = (const float*)d_in[9];
  const float* W2     = (const float*)d_in[10];
  const float* b2     = (const float*)d_in[11];
  float* out = (float*)d_out;

  const int* row = edge;
  const int* col = edge + N_EDGES;

  // workspace layout (bytes), 256B-aligned
  char* ws = (char*)d_ws;
  _Float16*  h16    = (_Float16*)(ws);                   //  51,200,000
  _Float16*  hout16 = (_Float16*)(ws + 51200000);        //  51,200,000
  int*       cursor = (int*)  (ws + 102400000);          //     800,000 (ends as exact degree)
  int*       ew     = (int*)  (ws + 103200000);          //  25,600,000 (CAP=32 buckets)
  _Float16*  WT     = (_Float16*)(ws + 128800000);       //     196,608

  // 4 dispatches; bin hidden in the gemm's occupancy tail
  k_prep0<<<(N_NODES + 255) / 256, 256, 0, stream>>>(cursor, W_conv, WT);
  k_fused<<<GEMM_TILES + BIN_BLKS, 256, 0, stream>>>(x, WT, h16, row, col, cursor, ew);
  k_gather<<<(((N_NODES + 3) / 4) * 64 + 255) / 256, 256, 0, stream>>>(h16, cursor, ew, b_conv, hout16);
  k_head<<<NG, 128, 0, stream>>>(x, batch, hout16, W0, b0, W1, b1, W2, b2, out);
}

// Round 22
// 286.386 us; speedup vs baseline: 1.3704x; 1.1491x over previous
//
#include <hip/hip_runtime.h>

#define N_NODES 200000
#define N_EDGES 800000
#define IN_DIM 768
#define HID 128
#define NG 1024
#define CAP 32   // per-node edge bucket capacity; deg ~ Poisson(4), P(overflow) ~ 3e-13

// MFMA GEMM tile (R18 proven config)
#define BM 128
#define BKT 32
#define NT (IN_DIM / BKT)     // 24
#define GEMM_TILES ((N_NODES + BM - 1) / BM)    // 1563

// bin tail blocks (appended after gemm blocks in the same dispatch)
#define BIN_BLKS 256
#define BIN_STRIDE (BIN_BLKS * 256)

typedef _Float16 f16x8 __attribute__((ext_vector_type(8)));
typedef float f32x4 __attribute__((ext_vector_type(4)));

__device__ __forceinline__ void gload_lds16(const void* g, void* l) {
  __builtin_amdgcn_global_load_lds((const __attribute__((address_space(1))) void*)g,
                                   (__attribute__((address_space(3))) void*)l, 16, 0, 0);
}
// non-temporal variant: aux=2 (NT/slc cpol bit) — x stream has zero reuse, keep it out of L2
__device__ __forceinline__ void gload_lds16_nt(const void* g, void* l) {
  __builtin_amdgcn_global_load_lds((const __attribute__((address_space(1))) void*)g,
                                   (__attribute__((address_space(3))) void*)l, 16, 0, 2);
}

__device__ inline void unpack16(unsigned u, float& a, float& b) {
  union { unsigned v; _Float16 f[2]; } c; c.v = u;
  a = (float)c.f[0]; b = (float)c.f[1];
}
__device__ inline unsigned pack16(float a, float b) {
  union { unsigned v; _Float16 f[2]; } c;
  c.f[0] = (_Float16)a; c.f[1] = (_Float16)b;
  return c.v;
}

// ---------------- prep0: zero cursor + W-transpose (one dispatch) ----------------
__global__ __launch_bounds__(256) void k_prep0(int* __restrict__ cursor,
                                               const float* __restrict__ W, _Float16* __restrict__ WT) {
  int gid = blockIdx.x * 256 + threadIdx.x;
  if (gid < N_NODES) cursor[gid] = 0;
  if (gid < IN_DIM * HID) {
    int k = gid / HID, n = gid % HID;
    WT[(size_t)n * IN_DIM + k] = (_Float16)W[gid];
  }
}

// ---------------- fused: gemm (blocks 0..GEMM_TILES) + bin (tail blocks) ----------------
__global__ __launch_bounds__(256, 3) void k_fused(const float* __restrict__ x,
                                                  const _Float16* __restrict__ WT,
                                                  _Float16* __restrict__ h16,
                                                  const int* __restrict__ row, const int* __restrict__ col,
                                                  int* __restrict__ cursor, int* __restrict__ ew) {
  __shared__ __align__(16) char arena[49152];   // 48 KB

  if (blockIdx.x >= GEMM_TILES) {
    // ---- bin branch (hidden in gemm occupancy tail) ----
    int gid = ((int)blockIdx.x - GEMM_TILES) * 256 + threadIdx.x;
    for (int e = gid; e < N_EDGES; e += BIN_STRIDE) {
      int c = col[e];
      int slot = atomicAdd(&cursor[c], 1);
      if (slot < CAP) ew[(size_t)c * CAP + slot] = row[e];
    }
    return;
  }

  // ---- gemm branch ----
  const int t = threadIdx.x;
  const int lane = t & 63;
  const int wid = t >> 6;
  const int bm = blockIdx.x * BM;

  f32x4 acc[2][8];
#pragma unroll
  for (int i = 0; i < 2; ++i)
#pragma unroll
    for (int j = 0; j < 8; ++j) acc[i][j] = (f32x4){0.f, 0.f, 0.f, 0.f};

  const int lr = lane & 15;
  const int s0 = (lane >> 4) * 2;
  const int bslot_r = lane >> 4;

  const int a_srow = lane >> 3;
  const int a_scol = ((lane & 7) ^ (lane >> 3)) * 4;
  const int b_srow = lane >> 2;
  const int b_scol = (((lane & 3) ^ ((lane >> 3) & 3)) * 8);

  auto stage = [&](int k0, int dbuf) {
    char* bA = arena + dbuf * 16384;
    char* bB = arena + 32768 + dbuf * 8192;
#pragma unroll
    for (int p = 0; p < 4; ++p) {
      int r = p * 32 + wid * 8 + a_srow;
      int grow = bm + r; if (grow >= N_NODES) grow = N_NODES - 1;
      gload_lds16_nt(x + (size_t)grow * IN_DIM + k0 + a_scol, bA + p * 4096 + wid * 1024);
    }
#pragma unroll
    for (int p = 0; p < 2; ++p) {
      int r = p * 64 + wid * 16 + b_srow;
      gload_lds16(WT + (size_t)r * IN_DIM + k0 + b_scol, bB + p * 4096 + wid * 1024);
    }
  };

  stage(0, 0);
  __syncthreads();

  for (int tt = 0; tt < NT; ++tt) {
    const int cur = tt & 1;
    if (tt + 1 < NT) stage((tt + 1) * BKT, cur ^ 1);

    const char* bA = arena + cur * 16384;
    const char* bB = arena + 32768 + cur * 8192;

    f16x8 af[2];
#pragma unroll
    for (int rt = 0; rt < 2; ++rt) {
      int r = wid * 32 + rt * 16 + lr;
      const char* rb = bA + r * 128;
      int f = r & 7;
      float4 lo = *(const float4*)(rb + ((s0 ^ f) << 4));
      float4 hi = *(const float4*)(rb + (((s0 + 1) ^ f) << 4));
      af[rt][0] = (_Float16)lo.x; af[rt][1] = (_Float16)lo.y;
      af[rt][2] = (_Float16)lo.z; af[rt][3] = (_Float16)lo.w;
      af[rt][4] = (_Float16)hi.x; af[rt][5] = (_Float16)hi.y;
      af[rt][6] = (_Float16)hi.z; af[rt][7] = (_Float16)hi.w;
    }
#pragma unroll
    for (int ct = 0; ct < 8; ++ct) {
      int cr = ct * 16 + lr;
      f16x8 bf = *(const f16x8*)(bB + cr * 64 + ((bslot_r ^ ((cr >> 1) & 3)) << 4));
      acc[0][ct] = __builtin_amdgcn_mfma_f32_16x16x32_f16(af[0], bf, acc[0][ct], 0, 0, 0);
      acc[1][ct] = __builtin_amdgcn_mfma_f32_16x16x32_f16(af[1], bf, acc[1][ct], 0, 0, 0);
    }
    __syncthreads();
  }

  _Float16* hb = (_Float16*)arena;
  const int dcol = lane & 15;
  const int drow = (lane >> 4) * 4;
#pragma unroll
  for (int rt = 0; rt < 2; ++rt)
#pragma unroll
    for (int j = 0; j < 4; ++j) {
      int rl = wid * 32 + rt * 16 + drow + j;
#pragma unroll
      for (int ct = 0; ct < 8; ++ct)
        hb[rl * HID + ct * 16 + dcol] = (_Float16)acc[rt][ct][j];
    }
  __syncthreads();
#pragma unroll
  for (int q = 0; q < 8; ++q) {
    int f = t + 256 * q;
    int rowl = f >> 4, seg = f & 15;
    int grow = bm + rowl;
    if (grow < N_NODES)
      ((uint4*)(h16 + (size_t)grow * HID))[seg] = ((const uint4*)hb)[f];
  }
}

// ---------------- gather: depth-2 pipelined node pairs (R18) ----------------
__global__ __launch_bounds__(256) void k_gather(const _Float16* __restrict__ h16,
                                                const int* __restrict__ cursor,
                                                const int* __restrict__ ew,
                                                const float* __restrict__ b_conv,
                                                _Float16* __restrict__ hout16) {
  int gid = blockIdx.x * 256 + threadIdx.x;
  int wv = gid >> 6, lane = gid & 63;
  int n0 = wv * 4;
  if (n0 >= N_NODES) return;
  const int grp = lane >> 4;
  const int fl = lane & 15;
  const int j32 = fl + 16 * grp;
  const unsigned* h32 = (const unsigned*)h16;
  unsigned* ho32 = (unsigned*)hout16;
  const float bc0 = b_conv[2 * j32], bc1 = b_conv[2 * j32 + 1];

#pragma unroll
  for (int p = 0; p < 2; ++p) {
    const int iA = n0 + 2 * p;
    const int iB = iA + 1;
    const bool vA = iA < N_NODES, vB = iB < N_NODES;
    const int cA_idx = vA ? iA : N_NODES - 1;
    const int cB_idx = vB ? iB : N_NODES - 1;

    int cntA = cursor[cA_idx];
    int cntB = cursor[cB_idx];
    unsigned selfA = h32[(size_t)cA_idx * 64 + j32];
    unsigned selfB = h32[(size_t)cB_idx * 64 + j32];
    int bkA = (grp < cntA) ? ew[(size_t)cA_idx * CAP + grp] : 0;
    int bkB = (grp < cntB) ? ew[(size_t)cB_idx * CAP + grp] : 0;

    float diA = rsqrtf((float)(cntA + 1));
    float diB = rsqrtf((float)(cntB + 1));
    int mA = cntA > CAP ? CAP : cntA;
    int mB = cntB > CAP ? CAP : cntB;

    float aA[8], aB[8];
#pragma unroll
    for (int q = 0; q < 8; ++q) { aA[q] = 0.f; aB[q] = 0.f; }

    {
      bool eA = grp < (mA < 4 ? mA : 4);
      bool eB = grp < (mB < 4 ? mB : 4);
      float wA = 0.f, wB = 0.f;
      unsigned uA0 = 0, uA1 = 0, uA2 = 0, uA3 = 0;
      unsigned uB0 = 0, uB1 = 0, uB2 = 0, uB3 = 0;
      if (eA) {
        wA = rsqrtf((float)(cursor[bkA] + 1)) * diA;
        const unsigned* hr = h32 + (size_t)bkA * 64;
        uA0 = hr[fl]; uA1 = hr[fl + 16]; uA2 = hr[fl + 32]; uA3 = hr[fl + 48];
      }
      if (eB) {
        wB = rsqrtf((float)(cursor[bkB] + 1)) * diB;
        const unsigned* hr = h32 + (size_t)bkB * 64;
        uB0 = hr[fl]; uB1 = hr[fl + 16]; uB2 = hr[fl + 32]; uB3 = hr[fl + 48];
      }
      float f0, f1;
      unpack16(uA0, f0, f1); aA[0] = fmaf(f0, wA, aA[0]); aA[1] = fmaf(f1, wA, aA[1]);
      unpack16(uA1, f0, f1); aA[2] = fmaf(f0, wA, aA[2]); aA[3] = fmaf(f1, wA, aA[3]);
      unpack16(uA2, f0, f1); aA[4] = fmaf(f0, wA, aA[4]); aA[5] = fmaf(f1, wA, aA[5]);
      unpack16(uA3, f0, f1); aA[6] = fmaf(f0, wA, aA[6]); aA[7] = fmaf(f1, wA, aA[7]);
      unpack16(uB0, f0, f1); aB[0] = fmaf(f0, wB, aB[0]); aB[1] = fmaf(f1, wB, aB[1]);
      unpack16(uB1, f0, f1); aB[2] = fmaf(f0, wB, aB[2]); aB[3] = fmaf(f1, wB, aB[3]);
      unpack16(uB2, f0, f1); aB[4] = fmaf(f0, wB, aB[4]); aB[5] = fmaf(f1, wB, aB[5]);
      unpack16(uB3, f0, f1); aB[6] = fmaf(f0, wB, aB[6]); aB[7] = fmaf(f1, wB, aB[7]);
    }

    int mMax = mA > mB ? mA : mB;
    for (int c = 4; c < mMax; c += 4) {
      bool eA = c + grp < mA;
      bool eB = c + grp < mB;
      int rA = eA ? ew[(size_t)iA * CAP + c + grp] : 0;
      int rB = eB ? ew[(size_t)iB * CAP + c + grp] : 0;
      float wA = 0.f, wB = 0.f;
      unsigned uA0 = 0, uA1 = 0, uA2 = 0, uA3 = 0;
      unsigned uB0 = 0, uB1 = 0, uB2 = 0, uB3 = 0;
      if (eA) {
        wA = rsqrtf((float)(cursor[rA] + 1)) * diA;
        const unsigned* hr = h32 + (size_t)rA * 64;
        uA0 = hr[fl]; uA1 = hr[fl + 16]; uA2 = hr[fl + 32]; uA3 = hr[fl + 48];
      }
      if (eB) {
        wB = rsqrtf((float)(cursor[rB] + 1)) * diB;
        const unsigned* hr = h32 + (size_t)rB * 64;
        uB0 = hr[fl]; uB1 = hr[fl + 16]; uB2 = hr[fl + 32]; uB3 = hr[fl + 48];
      }
      float f0, f1;
      unpack16(uA0, f0, f1); aA[0] = fmaf(f0, wA, aA[0]); aA[1] = fmaf(f1, wA, aA[1]);
      unpack16(uA1, f0, f1); aA[2] = fmaf(f0, wA, aA[2]); aA[3] = fmaf(f1, wA, aA[3]);
      unpack16(uA2, f0, f1); aA[4] = fmaf(f0, wA, aA[4]); aA[5] = fmaf(f1, wA, aA[5]);
      unpack16(uA3, f0, f1); aA[6] = fmaf(f0, wA, aA[6]); aA[7] = fmaf(f1, wA, aA[7]);
      unpack16(uB0, f0, f1); aB[0] = fmaf(f0, wB, aB[0]); aB[1] = fmaf(f1, wB, aB[1]);
      unpack16(uB1, f0, f1); aB[2] = fmaf(f0, wB, aB[2]); aB[3] = fmaf(f1, wB, aB[3]);
      unpack16(uB2, f0, f1); aB[4] = fmaf(f0, wB, aB[4]); aB[5] = fmaf(f1, wB, aB[5]);
      unpack16(uB3, f0, f1); aB[6] = fmaf(f0, wB, aB[6]); aB[7] = fmaf(f1, wB, aB[7]);
    }

#pragma unroll
    for (int q = 0; q < 8; ++q) {
      aA[q] += __shfl_xor(aA[q], 16);
      aA[q] += __shfl_xor(aA[q], 32);
      aB[q] += __shfl_xor(aB[q], 16);
      aB[q] += __shfl_xor(aB[q], 32);
    }
    float rA0 = aA[0], rA1 = aA[1], rB0 = aB[0], rB1 = aB[1];
    if (grp == 1) { rA0 = aA[2]; rA1 = aA[3]; rB0 = aB[2]; rB1 = aB[3]; }
    else if (grp == 2) { rA0 = aA[4]; rA1 = aA[5]; rB0 = aB[4]; rB1 = aB[5]; }
    else if (grp == 3) { rA0 = aA[6]; rA1 = aA[7]; rB0 = aB[6]; rB1 = aB[7]; }

    if (vA) {
      float swA = diA * diA, s0, s1;
      unpack16(selfA, s0, s1);
      float v0 = fmaxf(fmaf(s0, swA, rA0) + bc0, 0.f);
      float v1 = fmaxf(fmaf(s1, swA, rA1) + bc1, 0.f);
      ho32[(size_t)iA * 64 + j32] = pack16(v0, v1);
    }
    if (vB) {
      float swB = diB * diB, s0, s1;
      unpack16(selfB, s0, s1);
      float v0 = fmaxf(fmaf(s0, swB, rB0) + bc0, 0.f);
      float v1 = fmaxf(fmaf(s1, swB, rB1) + bc1, 0.f);
      ho32[(size_t)iB * 64 + j32] = pack16(v0, v1);
    }
  }
}

// ---------------- fused head (R21) ----------------
__global__ __launch_bounds__(128) void k_head(const float* __restrict__ x,
                                              const int* __restrict__ batch,
                                              const _Float16* __restrict__ hout16,
                                              const float* __restrict__ W0, const float* __restrict__ b0,
                                              const float* __restrict__ W1, const float* __restrict__ b1,
                                              const float* __restrict__ W2, const float* __restrict__ b2,
                                              float* __restrict__ out) {
  __shared__ float xr[IN_DIM];
  __shared__ float pl[HID];
  __shared__ float nn[HID];
  __shared__ float red[4];
  __shared__ int bounds[2];
  int g = blockIdx.x, t = threadIdx.x;

  if (t == 0 || t == 64) {
    int tgt = g + (t >> 6);
    int lo = 0, hi = N_NODES;
    while (lo < hi) { int mid = (lo + hi) >> 1; if (batch[mid] < tgt) lo = mid + 1; else hi = mid; }
    bounds[t >> 6] = lo;
  }
  __syncthreads();
  int lo = bounds[0], lo2 = bounds[1];
  int i0 = lo < N_NODES ? lo : N_NODES - 1;

  const unsigned* ho32 = (const unsigned*)hout16;
  const int u = t >> 1, half = t & 1;
  float m = 0.f;
  int r = lo;
  for (; r + 3 < lo2; r += 4) {
    unsigned a = ho32[(size_t)r * 64 + u];
    unsigned b = ho32[(size_t)(r + 1) * 64 + u];
    unsigned c = ho32[(size_t)(r + 2) * 64 + u];
    unsigned d = ho32[(size_t)(r + 3) * 64 + u];
    float a0, a1, b0v, b1v, c0, c1, d0, d1;
    unpack16(a, a0, a1); unpack16(b, b0v, b1v);
    unpack16(c, c0, c1); unpack16(d, d0, d1);
    m = fmaxf(m, half ? a1 : a0);
    m = fmaxf(m, half ? b1v : b0v);
    m = fmaxf(m, half ? c1 : c0);
    m = fmaxf(m, half ? d1 : d0);
  }
  for (; r < lo2; ++r) {
    unsigned a = ho32[(size_t)r * 64 + u];
    float a0, a1; unpack16(a, a0, a1);
    m = fmaxf(m, half ? a1 : a0);
  }
  pl[t] = m;

  const float* xp = x + (size_t)i0 * IN_DIM;
  for (int k = t; k < IN_DIM; k += 128) xr[k] = xp[k];
  __syncthreads();

  float a = b0[t];
#pragma unroll 8
  for (int k = 0; k < IN_DIM; ++k) a = fmaf(xr[k], W0[(size_t)k * HID + t], a);
  nn[t] = fmaxf(a, 0.f);
  __syncthreads();

  float z = b1[t];
#pragma unroll 8
  for (int k = 0; k < HID; ++k) z = fmaf(pl[k], W1[(size_t)k * HID + t], z);
#pragma unroll 8
  for (int k = 0; k < HID; ++k) z = fmaf(nn[k], W1[(size_t)(HID + k) * HID + t], z);
  z = fmaxf(z, 0.f);
  float p0 = z * W2[2 * t], p1 = z * W2[2 * t + 1];
#pragma unroll
  for (int o = 32; o > 0; o >>= 1) {
    p0 += __shfl_down(p0, o);
    p1 += __shfl_down(p1, o);
  }
  if ((t & 63) == 0) { red[(t >> 6) * 2] = p0; red[(t >> 6) * 2 + 1] = p1; }
  __syncthreads();
  if (t == 0) {
    float l0 = b2[0] + red[0] + red[2];
    float l1 = b2[1] + red[1] + red[3];
    float mm = fmaxf(l0, l1);
    float lse = mm + logf(expf(l0 - mm) + expf(l1 - mm));
    out[g * 2 + 0] = l0 - lse;
    out[g * 2 + 1] = l1 - lse;
  }
}

extern "C" void kernel_launch(void* const* d_in, const int* in_sizes, int n_in,
                              void* d_out, int out_size, void* d_ws, size_t ws_size,
                              hipStream_t stream) {
  const float* x      = (const float*)d_in[0];
  const int* edge     = (const int*)d_in[1];
  const int* batch    = (const int*)d_in[2];
  const float* W_conv = (const float*)d_in[4];
  const float* b_conv = (const float*)d_in[5];
  const float* W0     = (const float*)d_in[6];
  const float* b0     = (const float*)d_in[7];
  const float* W1     = (const float*)d_in[8];
  const float* b1     = (const float*)d_in[9];
  const float* W2     = (const float*)d_in[10];
  const float* b2     = (const float*)d_in[11];
  float* out = (float*)d_out;

  const int* row = edge;
  const int* col = edge + N_EDGES;

  // workspace layout (bytes), 256B-aligned
  char* ws = (char*)d_ws;
  _Float16*  h16    = (_Float16*)(ws);                   //  51,200,000
  _Float16*  hout16 = (_Float16*)(ws + 51200000);        //  51,200,000
  int*       cursor = (int*)  (ws + 102400000);          //     800,000 (ends as exact degree)
  int*       ew     = (int*)  (ws + 103200000);          //  25,600,000 (CAP=32 buckets)
  _Float16*  WT     = (_Float16*)(ws + 128800000);       //     196,608

  // 4 dispatches; bin hidden in the gemm's occupancy tail
  k_prep0<<<(N_NODES + 255) / 256, 256, 0, stream>>>(cursor, W_conv, WT);
  k_fused<<<GEMM_TILES + BIN_BLKS, 256, 0, stream>>>(x, WT, h16, row, col, cursor, ew);
  k_gather<<<(((N_NODES + 3) / 4) * 64 + 255) / 256, 256, 0, stream>>>(h16, cursor, ew, b_conv, hout16);
  k_head<<<NG, 128, 0, stream>>>(x, batch, hout16, W0, b0, W1, b1, W2, b2, out);
}